// Round 8
// baseline (243.934 us; speedup 1.0000x reference)
//
#include <hip/hip_runtime.h>

#define T_DIM 2048
#define B_DIM 8192
#define PH    256   // phases
#define SPH   8     // steps per phase

// DPP cross-lane helpers (pure VALU)
__device__ __forceinline__ float dpp_qxor1(float v) {
  int i = __float_as_int(v);
  return __int_as_float(__builtin_amdgcn_update_dpp(i, i, 0xB1, 0xF, 0xF, false)); // [1,0,3,2]
}
__device__ __forceinline__ float dpp_qxor2(float v) {
  int i = __float_as_int(v);
  return __int_as_float(__builtin_amdgcn_update_dpp(i, i, 0x4E, 0xF, 0xF, false)); // [2,3,0,1]
}
__device__ __forceinline__ float dpp_qxor3(float v) {
  int i = __float_as_int(v);
  return __int_as_float(__builtin_amdgcn_update_dpp(i, i, 0x1B, 0xF, 0xF, false)); // [3,2,1,0]
}
__device__ __forceinline__ float dpp_hmirror(float v) { // lane l <- lane l^7
  int i = __float_as_int(v);
  return __int_as_float(__builtin_amdgcn_update_dpp(i, i, 0x141, 0xF, 0xF, false));
}

__global__ __launch_bounds__(192) void lstm_pc4_kernel(
    const float* __restrict__ x,
    const float* __restrict__ w_ih, const float* __restrict__ w_hh,
    const float* __restrict__ b_ih, const float* __restrict__ b_hh,
    const float* __restrict__ w_lin, const float* __restrict__ b_lin,
    float* __restrict__ out)
{
  // Per-block (8 batch elems): xa as float2{A,B}; stride-9 float2 rows ->
  // banks (lane*18+2k) mod 32 cover all 32 banks exactly 4x per wave = minimum.
  __shared__ float2 xaBuf[2][64][9];
  __shared__ float  hnBuf[2][64][9];

  const int tid  = threadIdx.x;
  const int wid  = tid >> 6;       // 0: rec, 1: proj, 2: head
  const int lane = tid & 63;

  const float L2E = 1.4426950408889634f;
  const float cm2 = -2.0f * L2E;

  const int l = lane & 7;
  const int half1 = (l >> 2) & 1;            // 0: rows {i,g}; 1: rows {f,o}
  const int e = (l & 3) ^ (half1 ? 3 : 0);   // mirror partner owns same element
  const int grp = lane >> 3;
  const int rA = half1 * 4 + e;              // i | f row
  const int rB = 8 + half1 * 4 + e;          // g | o row
  const float sclA = -L2E;
  const float sclB = half1 ? -L2E : -2.0f * L2E;

  if (wid == 0) {
    // ---------------- recurrence wave: 257 barriers ----------------
    __builtin_amdgcn_s_setprio(1);
    float whhA[4], whhB[4];
    #pragma unroll
    for (int k = 0; k < 4; ++k) {
      const int j = e ^ k;
      whhA[k] = sclA * w_hh[rA * 4 + j];
      whhB[k] = sclB * w_hh[rB * 4 + j];
    }
    const float sB = half1 ? 1.0f : 2.0f * cm2;  // aB = sB*y + oB
    const float oB = half1 ? 0.0f : -cm2;
    float ct = 0.0f, h0 = 0.0f, h1 = 0.0f, h2 = 0.0f, h3 = 0.0f;

    __syncthreads();  // wait for proj to fill xaBuf[0]

    for (int p = 0; p < PH; ++p) {
      const int d = p & 1;
      float xaA[SPH], xaB[SPH];
      #pragma unroll
      for (int k = 0; k < SPH; ++k) {
        const float2 v = xaBuf[d][lane][k];   // ds_read_b64
        xaA[k] = v.x;
        xaB[k] = v.y;
      }
      #pragma unroll
      for (int k = 0; k < SPH; ++k) {
        float uA = fmaf(whhA[0], h0, xaA[k]);
        uA = fmaf(whhA[1], h1, uA);
        uA = fmaf(whhA[2], h2, uA);
        uA = fmaf(whhA[3], h3, uA);
        float uB = fmaf(whhB[0], h0, xaB[k]);
        uB = fmaf(whhB[1], h1, uB);
        uB = fmaf(whhB[2], h2, uB);
        uB = fmaf(whhB[3], h3, uB);
        const float aA = __builtin_amdgcn_rcpf(1.0f + __builtin_amdgcn_exp2f(uA));
        const float yB = __builtin_amdgcn_rcpf(1.0f + __builtin_amdgcn_exp2f(uB));
        const float aB = fmaf(sB, yB, oB);
        // exchange: half0 sends cm2*(i*tanh g), half1 sends f
        const float Z = half1 ? aA : aA * aB;
        const float W = dpp_hmirror(Z);
        const float F = half1 ? Z : W;
        const float P = half1 ? W : Z;
        ct = fmaf(F, ct, P);                       // ct is cm2-scaled c
        const float zc = __builtin_amdgcn_exp2f(ct);
        const float rc = __builtin_amdgcn_rcpf(1.0f + zc);
        const float Ox = dpp_hmirror(aB);          // ship o to half0
        const float ov = half1 ? aB : Ox;
        const float tc = fmaf(2.0f, rc, -1.0f);    // tanh(c)
        const float hn = ov * tc;
        h0 = hn;
        h1 = dpp_qxor1(hn);
        h2 = dpp_qxor2(hn);
        h3 = dpp_qxor3(hn);
        hnBuf[d][lane][k] = hn;
      }
      __syncthreads();
    }
  } else if (wid == 1) {
    // ---------------- proj/load wave: 257 barriers ----------------
    const int b = blockIdx.x * 8 + grp;
    float wihA[4], wihB[4];
    #pragma unroll
    for (int k = 0; k < 4; ++k) {
      const int j = e ^ k;
      wihA[k] = sclA * w_ih[rA * 4 + j];
      wihB[k] = sclB * w_ih[rB * 4 + j];
    }
    const float biasA = sclA * (b_ih[rA] + b_hh[rA]);
    const float biasB = sclB * (b_ih[rB] + b_hh[rB]);

    const int XS = B_DIM * 4;
    const int xoff = b * 4 + e;

    float xc[SPH], xn[SPH];

    auto load8 = [&](float (&dst)[SPH], int ph) {
      const int base = xoff + ((ph & (PH - 1)) * SPH) * XS;  // wrap: harmless
      #pragma unroll
      for (int k = 0; k < SPH; ++k) dst[k] = x[base + k * XS];
    };
    auto projWrite = [&](const float (&xr)[SPH], int dd) {
      #pragma unroll
      for (int k = 0; k < SPH; ++k) {
        const float xe = xr[k];
        const float x1 = dpp_qxor1(xe);
        const float x2 = dpp_qxor2(xe);
        const float x3 = dpp_qxor3(xe);
        float a = fmaf(wihA[0], xe, biasA);
        a = fmaf(wihA[1], x1, a);
        a = fmaf(wihA[2], x2, a);
        a = fmaf(wihA[3], x3, a);
        float bb = fmaf(wihB[0], xe, biasB);
        bb = fmaf(wihB[1], x1, bb);
        bb = fmaf(wihB[2], x2, bb);
        bb = fmaf(wihB[3], x3, bb);
        xaBuf[dd][lane][k] = make_float2(a, bb);   // ds_write_b64
      }
    };

    // prologue: xa for phase 0 -> buf0; start loading x for phase 1
    load8(xc, 0);
    projWrite(xc, 0);
    load8(xn, 1);
    __syncthreads();

    for (int pp = 0; pp < PH; pp += 2) {
      projWrite(xn, 1);           // xa(pp+1) -> buf1
      load8(xc, pp + 2);
      __syncthreads();
      projWrite(xc, 0);           // xa(pp+2) -> buf0
      load8(xn, pp + 3);
      __syncthreads();
    }
  } else {
    // ---------------- head/store wave: 257 barriers ----------------
    const int og = lane & 7, oj = lane >> 3;
    const int ob = blockIdx.x * 8 + og;
    float wl[4];
    #pragma unroll
    for (int j = 0; j < 4; ++j) wl[j] = -L2E * w_lin[j];
    const float blin = -L2E * b_lin[0];

    __syncthreads();  // initial barrier (matches other roles)

    for (int p = 0; p < PH; ++p) {
      __syncthreads();  // barrier ending phase p -> hnBuf[p&1] complete
      const int dh = p & 1;
      const float v0 = hnBuf[dh][og * 8 + 0][oj];
      const float v1 = hnBuf[dh][og * 8 + 1][oj];
      const float v2 = hnBuf[dh][og * 8 + 2][oj];
      const float v3 = hnBuf[dh][og * 8 + 3][oj];
      float m = fmaf(wl[0], v0, blin);
      m = fmaf(wl[1], v1, m);
      m = fmaf(wl[2], v2, m);
      m = fmaf(wl[3], v3, m);
      const float o = __builtin_amdgcn_rcpf(1.0f + __builtin_amdgcn_exp2f(m));
      out[(size_t)(p * SPH + oj) * B_DIM + ob] = o;
    }
  }
}

extern "C" void kernel_launch(void* const* d_in, const int* in_sizes, int n_in,
                              void* d_out, int out_size, void* d_ws, size_t ws_size,
                              hipStream_t stream) {
  const float* x     = (const float*)d_in[0];
  const float* w_ih  = (const float*)d_in[1];
  const float* w_hh  = (const float*)d_in[2];
  const float* b_ih  = (const float*)d_in[3];
  const float* b_hh  = (const float*)d_in[4];
  const float* w_lin = (const float*)d_in[5];
  const float* b_lin = (const float*)d_in[6];
  float* out = (float*)d_out;

  // 1024 blocks x 192 threads (1 rec + 1 proj + 1 head wave), 8 batch elems
  // per block. 3072 waves = 3/SIMD, but each SIMD hosts waves from ~3
  // INDEPENDENT blocks -> one block's barrier no longer idles the SIMD.
  dim3 block(192);
  dim3 grid(B_DIM / 8);
  hipLaunchKernelGGL(lstm_pc4_kernel, grid, block, 0, stream,
                     x, w_ih, w_hh, b_ih, b_hh, w_lin, b_lin, out);
}